// Round 1
// baseline (795.032 us; speedup 1.0000x reference)
//
#include <hip/hip_runtime.h>

#define NN 6144
#define BB 8
#define DD 16
#define KK 3
#define OO 64
#define CCOL 128   // B*D columns
#define BND (NN*DD) // 98304, per-b slab of inputs

typedef short short8 __attribute__((ext_vector_type(8)));
typedef float f32x4 __attribute__((ext_vector_type(4)));

__device__ __forceinline__ short f2bf(float f) {
    unsigned u = __builtin_bit_cast(unsigned, f);
    u = (u + 0x7FFFu + ((u >> 16) & 1u)) >> 16;   // RNE to bf16
    return (short)u;
}

// ---------------- prep: X^T bf16 [128][6144] and W re-laid [64][k*16+d] ----------------
__global__ void __launch_bounds__(256) prep_kernel(
    const float* __restrict__ xin, const float* __restrict__ W,
    unsigned short* __restrict__ Xt, float* __restrict__ Wl)
{
    int g = blockIdx.x * 256 + threadIdx.x;
    if (g < CCOL * NN) {
        int c = g / NN;
        int m = g - c * NN;
        int b = c >> 4, d = c & 15;
        float v = xin[(size_t)b * BND + m * DD + d];
        Xt[g] = (unsigned short)f2bf(v);
    } else if (g < CCOL * NN + OO * 48) {
        int i = g - CCOL * NN;
        int o = i / 48, j = i - o * 48;
        int k = j >> 4, d = j & 15;
        Wl[i] = W[o * 48 + d * 3 + k];   // Wl[o][k*16+d] = W[o][d*3+k]
    }
}

// ---------------- main: Y[k][n][c] = sup_k @ X  (+ identity) ----------------
// block = 128 threads (2 waves), tile = 32 rows x 128 cols, loop m in steps of 64
__global__ void __launch_bounds__(128) gemm_kernel(
    const float* __restrict__ sup, const float* __restrict__ xin,
    const unsigned short* __restrict__ Xt, float* __restrict__ Yws)
{
    __shared__ short lbuf[8192];  // 16 KB: [mgroup 0..7][c 0..127] blocks of 8 bf16

    const int tid = threadIdx.x;
    const int w   = tid >> 6;      // wave 0/1
    const int L   = tid & 63;
    const int q   = L >> 4;        // lane quad 0..3
    const int col = L & 15;
    const int n0  = blockIdx.x * 32;
    const int k   = blockIdx.y;

    const float* A    = sup + (size_t)k * NN * NN;
    const int    nrow = n0 + w * 16 + col;          // A row owned by this lane
    const float* arow = A + (size_t)nrow * NN;

    f32x4 acc[8];
#pragma unroll
    for (int i = 0; i < 8; ++i) acc[i] = (f32x4)0.0f;

    for (int m0 = 0; m0 < NN; m0 += 64) {
        // A: 16 fp32 per lane (k-slots mc*32 + q*8 + j), contiguous 256B per row per wave
        const float* ap = arow + m0 + q * 8;
        float4 a0 = *(const float4*)(ap);
        float4 a1 = *(const float4*)(ap + 4);
        float4 a2 = *(const float4*)(ap + 32);
        float4 a3 = *(const float4*)(ap + 36);

        // B: stage 64(m) x 128(c) bf16 tile via async global->LDS, 16B per thread per issue
#pragma unroll
        for (int i = 0; i < 8; ++i) {
            const unsigned short* src = Xt + (size_t)tid * NN + m0 + i * 8;
            short* dst = &lbuf[(i * 128 + tid) * 8];
            __builtin_amdgcn_global_load_lds(
                (const __attribute__((address_space(1))) unsigned int*)src,
                (__attribute__((address_space(3))) unsigned int*)dst, 16, 0, 0);
        }
        __syncthreads();  // drains vmcnt: A regs + LDS tile both ready

        short8 af0, af1;
        af0[0]=f2bf(a0.x); af0[1]=f2bf(a0.y); af0[2]=f2bf(a0.z); af0[3]=f2bf(a0.w);
        af0[4]=f2bf(a1.x); af0[5]=f2bf(a1.y); af0[6]=f2bf(a1.z); af0[7]=f2bf(a1.w);
        af1[0]=f2bf(a2.x); af1[1]=f2bf(a2.y); af1[2]=f2bf(a2.z); af1[3]=f2bf(a2.w);
        af1[4]=f2bf(a3.x); af1[5]=f2bf(a3.y); af1[6]=f2bf(a3.z); af1[7]=f2bf(a3.w);

#pragma unroll
        for (int cc = 0; cc < 8; ++cc) {
            short8 bf = *(const short8*)&lbuf[((0 * 4 + q) * 128 + cc * 16 + col) * 8];
            acc[cc] = __builtin_amdgcn_mfma_f32_16x16x32_bf16(af0, bf, acc[cc], 0, 0, 0);
        }
#pragma unroll
        for (int cc = 0; cc < 8; ++cc) {
            short8 bf = *(const short8*)&lbuf[((1 * 4 + q) * 128 + cc * 16 + col) * 8];
            acc[cc] = __builtin_amdgcn_mfma_f32_16x16x32_bf16(af1, bf, acc[cc], 0, 0, 0);
        }
        __syncthreads();  // protect lbuf before next stage
    }

    // epilogue: C/D layout col=lane&15, row=q*4+reg; add identity (fp32 inputs)
#pragma unroll
    for (int cc = 0; cc < 8; ++cc) {
#pragma unroll
        for (int r = 0; r < 4; ++r) {
            int nr = n0 + w * 16 + q * 4 + r;
            float v = acc[cc][r] + xin[(size_t)cc * BND + nr * DD + col]; // b=cc, d=col
            Yws[((size_t)k * NN + nr) * CCOL + cc * 16 + col] = v;
        }
    }
}

// ---------------- stage 2: out[b,n,o] = bias[o] + sum_j Y48[j] * Wl[o][j] ----------------
__global__ void __launch_bounds__(256) out_kernel(
    const float* __restrict__ Yws, const float* __restrict__ Wl,
    const float* __restrict__ bias, float* __restrict__ out)
{
    const int o   = threadIdx.x & 63;
    const int wid = blockIdx.x * 4 + (threadIdx.x >> 6);  // 2048 waves total

    float wreg[48];
#pragma unroll
    for (int j = 0; j < 12; ++j)
        *(float4*)&wreg[j * 4] = *(const float4*)&Wl[o * 48 + j * 4];
    const float bv = bias[o];

    for (int ii = 0; ii < 24; ++ii) {
        int p = wid * 24 + ii;          // p in [0, 49152)
        int b = p / NN;
        int n = p - b * NN;
        const float* yp = Yws + (size_t)n * CCOL + b * 16;
        float acc = bv;
#pragma unroll
        for (int k = 0; k < 3; ++k) {
#pragma unroll
            for (int d4 = 0; d4 < 4; ++d4) {
                float4 y = *(const float4*)(yp + k * (NN * CCOL) + d4 * 4);
                int j = k * 16 + d4 * 4;
                acc += y.x * wreg[j] + y.y * wreg[j + 1] + y.z * wreg[j + 2] + y.w * wreg[j + 3];
            }
        }
        out[(size_t)p * OO + o] = acc;
    }
}

extern "C" void kernel_launch(void* const* d_in, const int* in_sizes, int n_in,
                              void* d_out, int out_size, void* d_ws, size_t ws_size,
                              hipStream_t stream) {
    const float* xin  = (const float*)d_in[0];  // [8,6144,16]
    const float* sup  = (const float*)d_in[1];  // [3,6144,6144]
    const float* W    = (const float*)d_in[2];  // [64,48]
    const float* bias = (const float*)d_in[3];  // [64]
    float* out = (float*)d_out;                 // [8,6144,64]

    char* ws = (char*)d_ws;
    unsigned short* Xt = (unsigned short*)ws;            // 786432 * 2 B = 1572864
    float* Wl  = (float*)(ws + 1572864);                 // 3072 * 4 B  = 12288
    float* Yws = (float*)(ws + 1585152);                 // 2359296 * 4 B = 9437184

    prep_kernel<<<(CCOL * NN + OO * 48 + 255) / 256, 256, 0, stream>>>(xin, W, Xt, Wl);
    dim3 grid(NN / 32, KK);
    gemm_kernel<<<grid, 128, 0, stream>>>(sup, xin, Xt, Yws);
    out_kernel<<<512, 256, 0, stream>>>(Yws, Wl, bias, out);
}